// Round 12
// baseline (136.515 us; speedup 1.0000x reference)
//
#include <hip/hip_runtime.h>
#include <hip/hip_bf16.h>

#define BB 8
#define SS 4096
#define DD 1024
#define NN 64
#define ROWS (BB * SS)          // 32768
#define GLD 256                 // 4 gates * 64
#define NCHUNK 256              // chunks per sequence
#define CLEN 16                 // steps per chunk (NCHUNK*CLEN == SS)

typedef _Float16 f16;
using f16x8 = __attribute__((ext_vector_type(8))) _Float16;
using f32x4 = __attribute__((ext_vector_type(4))) float;

// ---------------- prep (merged): W' = ln_w ⊙ W packed fp16 sub-slices; Wp -> fp16; bias folds ----------------
// sub-slice s (16 KB): [cb(16)][lane(64)][8] ; element = W'[cb*16+(l&15)][s*32+(l>>4)*8+e]
__global__ __launch_bounds__(256) void prep_all(const float* __restrict__ Wi, const float* __restrict__ bi,
                                                const float* __restrict__ Wf, const float* __restrict__ bfv,
                                                const float* __restrict__ Wz, const float* __restrict__ bz,
                                                const float* __restrict__ Wo, const float* __restrict__ bo,
                                                const float* __restrict__ Wp,
                                                const float* __restrict__ ln_w, const float* __restrict__ ln_b,
                                                f16* __restrict__ Wpk, f16* __restrict__ Wpf,
                                                float* __restrict__ ball, float* __restrict__ e_all) {
    if (blockIdx.x < 384) {
        int i = blockIdx.x * 256 + threadIdx.x;
        if (i < 32768) {
            int l = i & 63, cb = (i >> 6) & 15, s = i >> 10;
            int r = cb * 16 + (l & 15);
            int c = s * 32 + (l >> 4) * 8;
            int g = r >> 6, rem = r & 63;
            const float* W = (g == 0) ? Wi : (g == 1) ? Wf : (g == 2) ? Wz : Wo;
            const float* src = W + rem * 1024 + c;
            const float* lwp = ln_w + c;
            f16x8 v;
            #pragma unroll
            for (int e = 0; e < 8; ++e) v[e] = (f16)(src[e] * lwp[e]);
            *reinterpret_cast<f16x8*>(Wpk + (size_t)s * 8192 + cb * 512 + l * 8) = v;
        } else if (i < 32768 + 65536) {
            int j = i - 32768;
            Wpf[j] = (f16)Wp[j];
        }
    } else {
        int j = (blockIdx.x - 384) * 4 + (threadIdx.x >> 6);
        int lane = threadIdx.x & 63;
        int g = j >> 6, rem = j & 63;
        const float* W  = (g == 0) ? Wi : (g == 1) ? Wf : (g == 2) ? Wz : Wo;
        const float* bs = (g == 0) ? bi : (g == 1) ? bfv : (g == 2) ? bz : bo;
        const float* row = W + rem * 1024;
        float d = 0.0f, e = 0.0f;
        #pragma unroll
        for (int t = 0; t < 16; ++t) {
            int k = lane + 64 * t;
            float w = row[k];
            e += ln_w[k] * w;
            d += ln_b[k] * w;
        }
        #pragma unroll
        for (int off = 1; off < 64; off <<= 1) {
            e += __shfl_xor(e, off);
            d += __shfl_xor(d, off);
        }
        if (lane == 0) { ball[j] = bs[rem] + d; e_all[j] = e; }
    }
}

// ---------------- fused LN + gate GEMM + scan phase A ----------------
// 512 thr = 8 waves (2M x 4N). Tile 128 x 256, BK=64, 16 steps. Grid 256 = 1 block/CU.
// Main loop identical to R9 (77us proven). LDS: one 96KB buffer aliased as
// {W dbuf 64KB | X dbuf 32KB} during the loop, then exactly float[128][192] for the
// fused chunk-scan (tile = 8 chunks of 16 timesteps, one per wave).
__global__ __launch_bounds__(512, 1) void gate_gemm(const float* __restrict__ x,
                                                    const f16* __restrict__ Wpk,
                                                    const float* __restrict__ ball,
                                                    const float* __restrict__ e_all,
                                                    float* __restrict__ gates,
                                                    float4* __restrict__ s4) {
    int bm = blockIdx.x * 128;
    int tid = threadIdx.x;
    int wid = tid >> 6, lane = tid & 63;
    int wm = wid >> 2, wn = wid & 3;     // wn == gate index
    int lrow = lane & 15, lkg = lane >> 4;
    int srow = tid >> 2, skg = tid & 3;  // x staging: row 0..127, 16-k group

    __shared__ __align__(16) char ldsbuf[98304];   // 96 KB: W dbuf [0,64K) + X dbuf [64K,96K)
    __shared__ float2 stats_lds[128];

    const float4* xrow = reinterpret_cast<const float4*>(x + (size_t)(bm + srow) * DD) + skg * 4;
    float4 A0, A1, A2, A3, B0, B1, B2, B3;
    uint4 W0, W1, W2, W3;
    const uint4* wsrc = reinterpret_cast<const uint4*>(Wpk) + wid * 256 + lane;

    auto loadA = [&](int s) { const float4* p = xrow + s * 16; A0 = p[0]; A1 = p[1]; A2 = p[2]; A3 = p[3]; };
    auto loadB = [&](int s) { const float4* p = xrow + s * 16; B0 = p[0]; B1 = p[1]; B2 = p[2]; B3 = p[3]; };
    auto loadW = [&](int s) { const uint4* p = wsrc + (size_t)s * 2048; W0 = p[0]; W1 = p[64]; W2 = p[128]; W3 = p[192]; };
    auto writeW = [&](int buf) {
        uint4* d = reinterpret_cast<uint4*>(ldsbuf + buf * 32768 + wid * 4096) + lane;
        d[0] = W0; d[64] = W1; d[128] = W2; d[192] = W3;
    };

    float s1 = 0.0f, s2 = 0.0f;
    auto writeXv = [&](float4 v0, float4 v1, float4 v2, float4 v3, int buf) {
        float xv[16] = {v0.x, v0.y, v0.z, v0.w, v1.x, v1.y, v1.z, v1.w,
                        v2.x, v2.y, v2.z, v2.w, v3.x, v3.y, v3.z, v3.w};
        f16x8 p0, p1;
        #pragma unroll
        for (int e = 0; e < 8; ++e) {
            s1 += xv[e] + xv[8 + e];
            s2 += xv[e] * xv[e] + xv[8 + e] * xv[8 + e];
            p0[e] = (f16)xv[e];
            p1[e] = (f16)xv[8 + e];
        }
        char* base = ldsbuf + 65536 + buf * 16384 + srow * 128;
        int r7 = srow & 7;
        *reinterpret_cast<f16x8*>(base + 16 * ((2 * skg) ^ r7))     = p0;
        *reinterpret_cast<f16x8*>(base + 16 * ((2 * skg + 1) ^ r7)) = p1;
    };

    f32x4 acc[4][4] = {};
    auto compute = [&](int buf) {
        #pragma unroll
        for (int h = 0; h < 2; ++h) {
            f16x8 a[4];
            #pragma unroll
            for (int mf = 0; mf < 4; ++mf) {
                int row = wm * 64 + mf * 16 + lrow;
                a[mf] = *reinterpret_cast<const f16x8*>(
                    ldsbuf + 65536 + buf * 16384 + row * 128 + 16 * ((4 * h + lkg) ^ (row & 7)));
            }
            #pragma unroll
            for (int nf = 0; nf < 4; ++nf) {
                int cb = wn * 4 + nf;
                f16x8 w = *reinterpret_cast<const f16x8*>(
                    ldsbuf + buf * 32768 + h * 16384 + cb * 1024 + lane * 16);
                #pragma unroll
                for (int mf = 0; mf < 4; ++mf)
                    acc[mf][nf] = __builtin_amdgcn_mfma_f32_16x16x32_f16(a[mf], w, acc[mf][nf], 0, 0, 0);
            }
        }
    };
    auto stepSync = [&]() {
        asm volatile("s_waitcnt lgkmcnt(0)" ::: "memory");
        __builtin_amdgcn_s_barrier();
        __builtin_amdgcn_sched_barrier(0);
    };

    // prologue: x(0),x(1),W(0) in regs; stage step 0; prefetch x(2), W(1)
    loadA(0); loadB(1); loadW(0);
    writeW(0);
    writeXv(A0, A1, A2, A3, 0);
    loadA(2); loadW(1);
    stepSync();

    for (int it = 0; it < 8; ++it) {
        int s = 2 * it;
        compute(0);
        writeW(1);
        writeXv(B0, B1, B2, B3, 1);
        if (s + 2 <= 15) loadW(s + 2);
        if (s + 3 <= 15) loadB(s + 3);
        stepSync();
        compute(1);
        if (s + 2 <= 15) {
            writeW(0);
            writeXv(A0, A1, A2, A3, 0);
        }
        if (s + 3 <= 15) loadW(s + 3);
        if (s + 4 <= 15) loadA(s + 4);
        stepSync();
    }

    // stats: 4 threads per row
    s1 += __shfl_xor(s1, 1); s2 += __shfl_xor(s2, 1);
    s1 += __shfl_xor(s1, 2); s2 += __shfl_xor(s2, 2);
    if ((tid & 3) == 0) {
        float mu = s1 * (1.0f / DD);
        float var = s2 * (1.0f / DD) - mu * mu;
        float rsd = rsqrtf(var + 1e-5f);
        float2 st; st.x = mu * rsd; st.y = rsd;
        stats_lds[srow] = st;
    }
    __syncthreads();

    // ---- epilogue: LN fold + activations -> global gates + glds (li/lf/z, all 128 rows) ----
    float* glds = reinterpret_cast<float*>(ldsbuf);   // float[128][192], exactly 96 KB
    int c0 = wn * 64;
    int rb = (lane >> 4) * 4;
    #pragma unroll
    for (int mf = 0; mf < 4; ++mf) {
        #pragma unroll
        for (int nf = 0; nf < 4; ++nf) {
            int col = c0 + nf * 16 + (lane & 15);
            float bc = ball[col];
            float ec = e_all[col];
            #pragma unroll
            for (int r = 0; r < 4; ++r) {
                int rl = wm * 64 + mf * 16 + rb + r;
                float2 st = stats_lds[rl];
                float v = acc[mf][nf][r] * st.y + bc - st.x * ec;
                float res;
                if (wn == 0 || wn == 1)      res = fminf(fmaxf(v, -20.0f), 20.0f);
                else if (wn == 2)            res = tanhf(v);
                else                         res = 1.0f / (1.0f + expf(-v));
                gates[(size_t)(bm + rl) * GLD + col] = res;
                if (wn < 3)
                    glds[rl * 192 + col] = res;
            }
        }
    }
    __syncthreads();

    // ---- fused scan phase A: wave wid scans chunk wid (rows wid*16..+15) ----
    int b = bm >> 12;
    int cb0 = (bm & 4095) >> 4;
    {
        int lr0 = wid * 16;
        float Lf = 0.0f, m = -1e30f, c = 0.0f;
        #pragma unroll
        for (int j = 0; j < 16; ++j) {
            const float* g = glds + (lr0 + j) * 192;
            float li = g[lane], lf = g[64 + lane], z = g[128 + lane];
            Lf += lf;
            float ma = m + lf;
            float mn = fmaxf(ma, li);
            c = __expf(ma - mn) * c + __expf(li - mn) * z;
            m = mn;
        }
        float4 v; v.x = Lf; v.y = m; v.z = c; v.w = 0.0f;
        s4[(size_t)(b * NCHUNK + cb0 + wid) * 64 + lane] = v;
    }
}

// ---------------- scan phase B: sequential compose, prefetch-16 pipeline ----------------
__global__ __launch_bounds__(64) void scan_b(const float4* __restrict__ s4,
                                             float2* __restrict__ c2) {
    int b = blockIdx.x;
    int n = threadIdx.x;
    size_t base = (size_t)b * NCHUNK * 64 + n;
    float c = 0.0f, m = 0.0f;   // reference init: c0=0, m0=0
    float4 cur[16];
    #pragma unroll
    for (int d = 0; d < 16; ++d) cur[d] = s4[base + (size_t)d * 64];
    for (int kb = 0; kb < NCHUNK; kb += 16) {
        float4 nxt[16];
        if (kb + 16 < NCHUNK) {
            #pragma unroll
            for (int d = 0; d < 16; ++d) nxt[d] = s4[base + (size_t)(kb + 16 + d) * 64];
        }
        #pragma unroll
        for (int d = 0; d < 16; ++d) {
            float2 ci; ci.x = m; ci.y = c;
            c2[base + (size_t)(kb + d) * 64] = ci;
            float4 v = cur[d];
            float ma = m + v.x;
            float mo = fmaxf(ma, v.y);
            c = expf(ma - mo) * c + expf(v.y - mo) * v.z;
            m = mo;
        }
        #pragma unroll
        for (int d = 0; d < 16; ++d) cur[d] = nxt[d];
    }
}

// ---------------- fused scan phase C + output projection ----------------
// 1024 blocks x 256 thr (4 waves). Block = 32 timesteps (2 chunks) x all 1024 out cols.
// Waves 0-1 replay the scan for their chunk into swizzled h-LDS; then 4 waves project.
__global__ __launch_bounds__(256) void out_fused(const float* __restrict__ gates,
                                                 const float2* __restrict__ c2,
                                                 const f16* __restrict__ Wpf,
                                                 const float* __restrict__ bp,
                                                 float* __restrict__ out) {
    int tid = threadIdx.x, wid = tid >> 6, lane = tid & 63;
    int r0 = blockIdx.x * 32;                 // global row (b*4096 + t0)
    int b = r0 >> 12;
    int k0 = (r0 & 4095) >> 4;                // first chunk of this block

    __shared__ __align__(16) f16 hlds[32 * 64];   // [row][slot^(row&7)][8] swizzled

    if (wid < 2) {
        int k = k0 + wid;
        float2 ci = c2[((size_t)b * NCHUNK + k) * 64 + lane];
        float m = ci.x, c = ci.y;
        const float* gp = gates + (size_t)(r0 + wid * 16) * GLD + lane;
        #pragma unroll
        for (int t = 0; t < 16; ++t) {
            float li = gp[0], lf = gp[64], z = gp[128], o = gp[192];
            gp += GLD;
            float ma = m + lf;
            float mn = fmaxf(ma, li);
            c = __expf(ma - mn) * c + __expf(li - mn) * z;
            m = mn;
            int row = wid * 16 + t;
            hlds[row * 64 + (((lane >> 3) ^ (row & 7)) << 3) + (lane & 7)] = (f16)(o * tanhf(c));
        }
    }
    __syncthreads();

    int c0 = wid * 256;
    int lrow = lane & 15, lkg = lane >> 4;
    f32x4 acc[2][16] = {};
    #pragma unroll
    for (int ks = 0; ks < 2; ++ks) {
        int kk = ks * 32;
        f16x8 a[2];
        #pragma unroll
        for (int mf = 0; mf < 2; ++mf) {
            int row = mf * 16 + lrow;
            int slot = (kk >> 3) + lkg;
            a[mf] = *reinterpret_cast<const f16x8*>(&hlds[row * 64 + ((slot ^ (row & 7)) << 3)]);
        }
        #pragma unroll
        for (int nf = 0; nf < 16; ++nf) {
            f16x8 bfr = *reinterpret_cast<const f16x8*>(Wpf + (size_t)(c0 + nf * 16 + lrow) * NN + kk + lkg * 8);
            #pragma unroll
            for (int mf = 0; mf < 2; ++mf)
                acc[mf][nf] = __builtin_amdgcn_mfma_f32_16x16x32_f16(a[mf], bfr, acc[mf][nf], 0, 0, 0);
        }
    }
    int rb = lkg * 4;
    #pragma unroll
    for (int nf = 0; nf < 16; ++nf) {
        int col = c0 + nf * 16 + lrow;
        float bias = bp[col];
        #pragma unroll
        for (int mf = 0; mf < 2; ++mf) {
            #pragma unroll
            for (int r = 0; r < 4; ++r) {
                int row = r0 + mf * 16 + rb + r;
                out[(size_t)row * DD + col] = acc[mf][nf][r] + bias;
            }
        }
    }
}

extern "C" void kernel_launch(void* const* d_in, const int* in_sizes, int n_in,
                              void* d_out, int out_size, void* d_ws, size_t ws_size,
                              hipStream_t stream) {
    const float* x    = (const float*)d_in[0];
    const float* ln_w = (const float*)d_in[1];
    const float* ln_b = (const float*)d_in[2];
    const float* Wi   = (const float*)d_in[3];
    const float* bi   = (const float*)d_in[4];
    const float* Wf   = (const float*)d_in[5];
    const float* bfv  = (const float*)d_in[6];
    const float* Wz   = (const float*)d_in[7];
    const float* bz   = (const float*)d_in[8];
    const float* Wo   = (const float*)d_in[9];
    const float* bo   = (const float*)d_in[10];
    const float* Wp   = (const float*)d_in[11];
    const float* bp   = (const float*)d_in[12];
    float* out = (float*)d_out;

    // All scratch in d_ws (~37.5 MB; ws is ~512 MB). d_out written only by out_fused.
    char* w = (char*)d_ws;
    float* gates = (float*)w;  w += (size_t)ROWS * GLD * 4;          // 33,554,432
    float4* s4   = (float4*)w; w += (size_t)BB * NCHUNK * 64 * 16;   // 2,097,152
    float2* c2   = (float2*)w; w += (size_t)BB * NCHUNK * 64 * 8;    // 1,048,576
    f16* Wpk     = (f16*)w;    w += 32 * 8192 * 2;                   // 524,288
    f16* Wpf     = (f16*)w;    w += 1024 * 64 * 2;                   // 131,072
    float* ball  = (float*)w;  w += 256 * 4;                         // 1,024
    float* e_all = (float*)w;  w += 256 * 4;                         // 1,024

    prep_all<<<448, 256, 0, stream>>>(Wi, bi, Wf, bfv, Wz, bz, Wo, bo, Wp,
                                      ln_w, ln_b, Wpk, Wpf, ball, e_all);
    gate_gemm<<<ROWS / 128, 512, 0, stream>>>(x, Wpk, ball, e_all, gates, s4);
    scan_b<<<BB, 64, 0, stream>>>(s4, c2);
    out_fused<<<ROWS / 32, 256, 0, stream>>>(gates, c2, Wpf, bp, out);
}